// Round 3
// baseline (26914.359 us; speedup 1.0000x reference)
//
#include <hip/hip_runtime.h>

// ============================================================================
// Persistent dataflow kernel for attention-LSTM encoder.
// B=512, T-1=99, N=128, H=256.
// R3: ALL global inputs/outputs are FLOAT32 (per reference dtypes). Rounds 1-2
// read f32 arrays as bf16 -> low mantissa halfwords decoded as bf16-NaN ->
// NaN output. LDS staging & MFMA operands remain bf16 (inputs are
// bf16-quantized per the harness's bf16 floor threshold => conversion exact).
//
// 512 blocks x 256 threads, 2 blocks/CU. Block i:
//   A-role: attention for batch i  (z2 slice in LDS bf16, computed in prologue)
//   B-role: gates+LSTM for (bg=i/32, units js*8..js*8+7), W-slice in LDS bf16
// Handoff: flagA[b] (A(t) done -> w f32 in d_out + bf16 in wbf), flagB[bg]
// counter (B(t) done -> h in hbuf + z1 partials). Monotone flags, system-scope
// fences (correctness-first; relax later). Each 32-block group is a closed
// dependency system => deadlock-free at any occupancy.
// c stays fp32 in registers for the whole recurrence.
// ============================================================================

typedef unsigned int  uint32;
typedef unsigned short u16;
typedef float  f4  __attribute__((ext_vector_type(4)));
typedef short  s8v __attribute__((ext_vector_type(8)));   // 8 bf16 (guide §3)

#define TS 99
#define BB 512
#define NN 128
#define HH 256

__device__ __forceinline__ float bf2f(u16 u){
  union { uint32 i; float f; } v; v.i = ((uint32)u) << 16; return v.f;
}
__device__ __forceinline__ u16 f2bf(float f){
  union { float f; uint32 i; } v; v.f = f;
  uint32 r = v.i + 0x7FFFu + ((v.i >> 16) & 1u);   // RNE (finite values only)
  return (u16)(r >> 16);
}
__device__ __forceinline__ float frcp(float x){ return __builtin_amdgcn_rcpf(x); }
__device__ __forceinline__ float ftanh(float x){
  float t = __expf(2.f * x);          // saturates correctly on overflow
  return 1.f - 2.f * frcp(t + 1.f);
}
__device__ __forceinline__ float fsig(float x){
  return frcp(1.f + __expf(-x));
}

struct KParams {
  const float *in, *W1, *b1, *W2, *b2, *W3, *Wih, *Whh, *bih, *bhh;
  float *out;        // [weighted B*99*128 | encoded B*99*256] f32
  uint32 *flagA;     // [512]
  uint32 *flagB;     // [16]
  u16 *hbuf;         // [2][512][256] bf16 (MFMA operand copy of h)
  u16 *wbf;          // [512][128] bf16 (MFMA operand copy of w, single-buffer)
  float *z1part;     // [2][16][32 lb][32 js][99 s] fp32
};

__global__ __launch_bounds__(256, 2) void enc_kernel(KParams p)
{
  __shared__ __align__(16) u16   z2s[128 * 100];   // z2[n][s] bf16 (+b2), 25.6KB
  __shared__ __align__(16) u16   ubuf[12800];      // in_t[128][100] then Wsl[32][392]
  __shared__ __align__(16) u16   W1c[99 * 16];     // W1 cols for (h-units | c-units)
  __shared__ __align__(16) float biasv[32];
  __shared__ __align__(16) float uni[1056];        // gates[32][33] | ep[256]+efin[128]
  __shared__ __align__(16) float z1s[100];
  __shared__ __align__(16) float hcn[32 * 16];     // per-batch [h0..7, c0..7]
  __shared__ __align__(16) float w3s[100];
  __shared__ __align__(16) float b1s[100];
  __shared__ __align__(16) float red[2];

  const int tid = threadIdx.x;
  const int blk = blockIdx.x;
  const int bA  = blk;        // A-role batch
  const int bg  = blk >> 5;   // B-role batch group (32 batches)
  const int lbA = blk & 31;   // local index of bA within its group
  const int js  = blk & 31;   // B-role unit slice (units js*8 .. js*8+7)

  float* outw = p.out;
  float* oute = p.out + (size_t)BB * TS * NN;

  // ---------------- prologue ----------------
  // stage input[bA] transposed into ubuf as in_t[n][t] (f32 -> bf16, exact for
  // bf16-quantized inputs)
  {
    const float* src = p.in + (size_t)bA * TS * NN;
    for (int idx = tid; idx < TS * NN; idx += 256) {
      int t = idx >> 7, n = idx & 127;
      ubuf[n * 100 + t] = f2bf(src[idx]);
    }
  }
  __syncthreads();
  // z2s[n][s] = b2[s] + sum_t in_t[n][t] * W2[s][t]
  {
    int n = tid >> 1, sc = tid & 1;
    int s0 = sc * 50, s1 = sc ? 99 : 50;
    for (int s = s0; s < s1; ++s) {
      float acc = p.b2[s];
      const float* w2r = p.W2 + s * TS;
      const u16* itr = &ubuf[n * 100];
      for (int t = 0; t + 1 < TS; t += 2) {
        acc = fmaf(bf2f(itr[t]),     w2r[t],     acc);
        acc = fmaf(bf2f(itr[t + 1]), w2r[t + 1], acc);
      }
      acc = fmaf(bf2f(itr[98]), w2r[98], acc);
      z2s[n * 100 + s] = f2bf(acc);
    }
  }
  __syncthreads();
  // overwrite ubuf with Wsl[32 rows][392]; row r=g*8+ul <-> global row g*256+js*8+ul
  {
    int r = tid >> 3, kc = tid & 7;
    int g = r >> 3, ul = r & 7;
    int grow = g * 256 + js * 8 + ul;
    const float* wihr = p.Wih + (size_t)grow * 128;
    const float* whhr = p.Whh + (size_t)grow * 256;
    for (int k = kc; k < 384; k += 8)
      ubuf[r * 392 + k] = f2bf((k < 128) ? wihr[k] : whhr[k - 128]);
    if (tid < 32) {
      int g2 = tid >> 3, ul2 = tid & 7;
      int gr = g2 * 256 + js * 8 + ul2;
      biasv[tid] = p.bih[gr] + p.bhh[gr];
    }
    for (int idx = tid; idx < 99 * 16; idx += 256) {
      int s = idx >> 4, j = idx & 15;
      int col = (j < 8) ? (js * 8 + j) : (256 + js * 8 + (j - 8));
      W1c[idx] = f2bf(p.W1[s * 512 + col]);
    }
    for (int s = tid; s < 99; s += 256) {
      w3s[s] = p.W3[s];
      b1s[s] = p.b1[s];
    }
  }
  __syncthreads();

  float creg = 0.f;   // LSTM cell state for (lb=tid>>3, ul=tid&7), fp32 forever

  for (int t = 0; t < TS; ++t) {
    const int par = t & 1;
    // ================= A phase: attention for batch bA =================
    if (t > 0) {
      if (tid == 0) {
        uint32 tgt = 32u * (uint32)t;
        while (__hip_atomic_load(&p.flagB[bg], __ATOMIC_ACQUIRE,
                                 __HIP_MEMORY_SCOPE_SYSTEM) < tgt)
          __builtin_amdgcn_s_sleep(1);
      }
      __syncthreads();
      __threadfence_system();   // acquire: invalidate local caches
    }
    // z1[s] = b1[s] + sum_js z1part[par][bg][lbA][js][s]
    {
      const float* zp = p.z1part + (((size_t)par * 16 + bg) * 32 + lbA) * 32 * 99;
      for (int s = tid; s < 99; s += 256) {
        float v = b1s[s];
        #pragma unroll 8
        for (int j = 0; j < 32; ++j) v += zp[j * 99 + s];
        z1s[s] = v;
      }
    }
    __syncthreads();
    // e[n] = sum_s w3[s] * tanh(z1[s] + z2[n][s])
    {
      int n = tid >> 1, hf = tid & 1;
      int s0 = hf * 50, s1 = hf ? 99 : 50;
      const u16* z2r = &z2s[n * 100];
      float acc = 0.f;
      for (int s = s0; s < s1; ++s) {
        float x = ftanh(z1s[s] + bf2f(z2r[s]));
        acc = fmaf(w3s[s], x, acc);
      }
      uni[tid] = acc;
    }
    __syncthreads();
    float* efin = uni + 256;
    if (tid < 128) efin[tid] = uni[2 * tid] + uni[2 * tid + 1];
    __syncthreads();
    if (tid < 64) {            // softmax reduce over 128 (b3 is shift-invariant)
      float v0 = efin[tid], v1 = efin[tid + 64];
      float m = fmaxf(v0, v1);
      for (int off = 32; off; off >>= 1) m = fmaxf(m, __shfl_xor(m, off));
      float sm = __expf(v0 - m) + __expf(v1 - m);
      for (int off = 32; off; off >>= 1) sm += __shfl_xor(sm, off);
      if (tid == 0) { red[0] = m; red[1] = frcp(sm); }
    }
    __syncthreads();
    if (tid < 128) {
      float a  = __expf(efin[tid] - red[0]) * red[1];
      float xv = p.in[((size_t)bA * TS + t) * NN + tid];
      float w  = a * xv;
      outw[((size_t)bA * TS + t) * NN + tid] = w;   // f32 output
      p.wbf[bA * NN + tid] = f2bf(w);               // bf16 MFMA operand
    }
    __threadfence_system();    // release w
    __syncthreads();
    if (tid == 0)
      __hip_atomic_store(&p.flagA[bA], (uint32)(t + 1), __ATOMIC_RELEASE,
                         __HIP_MEMORY_SCOPE_SYSTEM);

    // ================= B phase: gates+LSTM for (bg, js) =================
    if (tid < 32) {
      uint32 tgt = (uint32)(t + 1);
      while (__hip_atomic_load(&p.flagA[bg * 32 + tid], __ATOMIC_ACQUIRE,
                               __HIP_MEMORY_SCOPE_SYSTEM) < tgt)
        __builtin_amdgcn_s_sleep(1);
    }
    __syncthreads();
    __threadfence_system();    // acquire: fresh wbf + hbuf
    // gates[32 batches][32 rows] via 4 waves of 16x16x32 bf16 MFMA, K=384
    {
      int wv = tid >> 6, lane = tid & 63;
      int mi = wv & 1, ni = wv >> 1;
      int bb = bg * 32 + mi * 16 + (lane & 15);
      int q8 = (lane >> 4) * 8;
      int nr = ni * 16 + (lane & 15);
      const u16* wrow = p.wbf + (size_t)bb * NN;
      const u16* hrow = p.hbuf + ((size_t)par * BB + bb) * HH;
      const u16* wslr = &ubuf[nr * 392];
      f4 acc = {0.f, 0.f, 0.f, 0.f};
      #pragma unroll
      for (int ks = 0; ks < 12; ++ks) {
        int k0 = ks * 32 + q8;
        const s8v* ap = (const s8v*)((k0 < 128) ? (wrow + k0) : (hrow + (k0 - 128)));
        const s8v* bp = (const s8v*)(wslr + k0);
        acc = __builtin_amdgcn_mfma_f32_16x16x32_bf16(*ap, *bp, acc, 0, 0, 0);
      }
      // C/D: col=lane&15 (weight row), row=(lane>>4)*4+i (batch)  [m89/m91]
      int mrow = mi * 16 + (lane >> 4) * 4;
      #pragma unroll
      for (int i = 0; i < 4; ++i)
        uni[(mrow + i) * 33 + nr] = acc[i];
    }
    __syncthreads();
    // LSTM pointwise: thread = (lb, ul)
    {
      int lb = tid >> 3, ul = tid & 7;
      float iv = uni[lb * 33 + ul]       + biasv[ul];
      float fv = uni[lb * 33 + 8 + ul]   + biasv[8 + ul];
      float gv = uni[lb * 33 + 16 + ul]  + biasv[16 + ul];
      float ov = uni[lb * 33 + 24 + ul]  + biasv[24 + ul];
      float cn = fsig(fv) * creg + fsig(iv) * ftanh(gv);
      float hn = fsig(ov) * ftanh(cn);
      creg = cn;
      int bb = bg * 32 + lb, u = js * 8 + ul;
      p.hbuf[((size_t)((t + 1) & 1) * BB + bb) * HH + u] = f2bf(hn);
      oute[((size_t)bb * TS + t) * HH + u] = hn;    // f32 output
      hcn[lb * 16 + ul]     = hn;
      hcn[lb * 16 + 8 + ul] = cn;
    }
    __syncthreads();
    // z1 partial for step t+1 from register-fresh h,c (16 K-columns)
    {
      int lb = tid >> 3, sc = tid & 7;
      int p2 = (t + 1) & 1;
      float* zp = p.z1part + ((((size_t)p2 * 16 + bg) * 32 + lb) * 32 + js) * 99;
      const float* hc = &hcn[lb * 16];
      for (int s = sc; s < 99; s += 8) {
        const u16* wr = &W1c[s * 16];
        float v = 0.f;
        #pragma unroll
        for (int j = 0; j < 16; ++j)
          v = fmaf(hc[j], bf2f(wr[j]), v);
        zp[s] = v;
      }
    }
    __threadfence_system();    // release h, z1part
    __syncthreads();
    if (tid == 0)
      __hip_atomic_fetch_add(&p.flagB[bg], 1u, __ATOMIC_RELEASE,
                             __HIP_MEMORY_SCOPE_SYSTEM);
  }
}

extern "C" void kernel_launch(void* const* d_in, const int* in_sizes, int n_in,
                              void* d_out, int out_size, void* d_ws, size_t ws_size,
                              hipStream_t stream)
{
  KParams p;
  p.in  = (const float*)d_in[0];
  p.W1  = (const float*)d_in[1];
  p.b1  = (const float*)d_in[2];
  p.W2  = (const float*)d_in[3];
  p.b2  = (const float*)d_in[4];
  p.W3  = (const float*)d_in[5];
  // d_in[6] = b3: softmax shift-invariant, unused
  p.Wih = (const float*)d_in[7];
  p.Whh = (const float*)d_in[8];
  p.bih = (const float*)d_in[9];
  p.bhh = (const float*)d_in[10];
  p.out = (float*)d_out;

  char* ws = (char*)d_ws;
  const size_t offFlagB  = 2048;
  const size_t offHbuf   = 4096;
  const size_t hbufBytes = 2ull * BB * HH * 2;                 // 524,288
  const size_t offWbf    = offHbuf + hbufBytes;                // 528,384
  const size_t wbfBytes  = (size_t)BB * NN * 2;                // 131,072
  const size_t offZ1     = offWbf + wbfBytes;                  // 659,456
  const size_t z1Bytes   = 2ull * 16 * 32 * 32 * 99 * 4;       // 12,976,128
  const size_t needBytes = offZ1 + z1Bytes;                    // ~13.6 MB
  if (ws_size < needBytes) return;  // ws too small: fail loudly (poison output)

  p.flagA  = (uint32*)ws;
  p.flagB  = (uint32*)(ws + offFlagB);
  p.hbuf   = (u16*)(ws + offHbuf);
  p.wbf    = (u16*)(ws + offWbf);
  p.z1part = (float*)(ws + offZ1);

  // zero everything the kernel may read before first write
  hipMemsetAsync(d_ws, 0, needBytes, stream);

  enc_kernel<<<dim3(512), dim3(256), 0, stream>>>(p);
}

// Round 4
// 5262.223 us; speedup vs baseline: 5.1146x; 5.1146x over previous
//
#include <hip/hip_runtime.h>

// ============================================================================
// Persistent dataflow kernel for attention-LSTM encoder.
// B=512, T-1=99, N=128, H=256. f32 global I/O, bf16 LDS/MFMA internals.
//
// R4: R3 passed but spent 99% of time in cache-maintenance ops: system-scope
// fences (buffer_wbl2+buffer_inv per wave per step) + ACQUIRE polls (one
// buffer_inv per poll iteration) serialized at the per-XCD L2s (~270us/step).
// Fix: ALL cross-block traffic via RELAXED AGENT-scope atomics (sc1 loads/
// stores -> L3 coherence point, no L2 maintenance). Release = s_waitcnt(0)
// [+barrier] + relaxed flag store; acquire = relaxed poll loop (control dep)
// + __syncthreads. Zero wbl2/inv in the hot loop.
//
// 512 blocks x 256 threads, 2 blocks/CU. Block i:
//   A-role: attention for batch i  (z2 slice in LDS bf16, from prologue)
//   B-role: gates+LSTM for (bg=i/32, units js*8..js*8+7), W-slice in LDS bf16
// h-fragments for the gates MFMA are loaded at step start (gated on flagB
// only) and consumed after the A-phase -> L3 latency hidden under A compute.
// Each 32-block group is a closed dependency system => deadlock-free at any
// occupancy. c stays fp32 in registers for the whole recurrence.
// ============================================================================

typedef unsigned int  uint32;
typedef unsigned long long ull;
typedef unsigned short u16;
typedef float  f4  __attribute__((ext_vector_type(4)));
typedef short  s8v __attribute__((ext_vector_type(8)));   // 8 bf16

#define TS 99
#define BB 512
#define NN 128
#define HH 256

__device__ __forceinline__ float bf2f(u16 u){
  union { uint32 i; float f; } v; v.i = ((uint32)u) << 16; return v.f;
}
__device__ __forceinline__ u16 f2bf(float f){
  union { float f; uint32 i; } v; v.f = f;
  uint32 r = v.i + 0x7FFFu + ((v.i >> 16) & 1u);   // RNE (finite values only)
  return (u16)(r >> 16);
}
__device__ __forceinline__ float frcp(float x){ return __builtin_amdgcn_rcpf(x); }
__device__ __forceinline__ float ftanh(float x){
  float t = __expf(2.f * x);
  return 1.f - 2.f * frcp(t + 1.f);
}
__device__ __forceinline__ float fsig(float x){
  return frcp(1.f + __expf(-x));
}

// L3-coherence-point accesses (global_load/store ... sc1; no L2 maintenance)
__device__ __forceinline__ uint32 ld32(const uint32* p){
  return __hip_atomic_load(p, __ATOMIC_RELAXED, __HIP_MEMORY_SCOPE_AGENT);
}
__device__ __forceinline__ ull ld64(const ull* p){
  return __hip_atomic_load(p, __ATOMIC_RELAXED, __HIP_MEMORY_SCOPE_AGENT);
}
__device__ __forceinline__ void st32(uint32* p, uint32 v){
  __hip_atomic_store(p, v, __ATOMIC_RELAXED, __HIP_MEMORY_SCOPE_AGENT);
}
__device__ __forceinline__ void st64(ull* p, ull v){
  __hip_atomic_store(p, v, __ATOMIC_RELAXED, __HIP_MEMORY_SCOPE_AGENT);
}
__device__ __forceinline__ float ldf(const float* p){
  union { uint32 i; float f; } v; v.i = ld32((const uint32*)p); return v.f;
}
__device__ __forceinline__ void stf(float* p, float x){
  union { float f; uint32 i; } v; v.f = x; st32((uint32*)p, v.i);
}

struct KParams {
  const float *in, *W1, *b1, *W2, *b2, *W3, *Wih, *Whh, *bih, *bhh;
  float *out;        // [weighted B*99*128 | encoded B*99*256] f32
  uint32 *flagA;     // [512]
  uint32 *flagB;     // [16]
  u16 *hbuf;         // [2][512][256] bf16 (MFMA operand copy of h)
  u16 *wbf;          // [512][128] bf16 (MFMA operand copy of w, single-buffer)
  float *z1part;     // [2][16][32 lb][32 js][99 s] fp32
};

__global__ __launch_bounds__(256, 2) void enc_kernel(KParams p)
{
  __shared__ __align__(16) u16   z2s[128 * 100];   // z2[n][s] bf16 (+b2)
  __shared__ __align__(16) u16   ubuf[12800];      // in_t[128][100] then Wsl[32][392]
  __shared__ __align__(16) u16   W1c[99 * 16];     // W1 cols (h-units | c-units)
  __shared__ __align__(16) float biasv[32];
  __shared__ __align__(16) float uni[1056];        // gates[32][33] | ep[256]+efin[128]
  __shared__ __align__(16) float z1s[100];
  __shared__ __align__(16) float zsum[200];        // z1 partial halves
  __shared__ __align__(16) float hcn[32 * 16];     // per-batch [h0..7, c0..7]
  __shared__ __align__(16) float w3s[100];
  __shared__ __align__(16) float b1s[100];

  const int tid = threadIdx.x;
  const int blk = blockIdx.x;
  const int bA  = blk;        // A-role batch
  const int bg  = blk >> 5;   // B-role batch group (32 batches)
  const int lbA = blk & 31;   // local index of bA within its group
  const int js  = blk & 31;   // B-role unit slice (units js*8 .. js*8+7)

  float* outw = p.out;
  float* oute = p.out + (size_t)BB * TS * NN;

  // wave-role constants for the gates MFMA
  const int wv   = tid >> 6, lane = tid & 63;
  const int mi   = wv & 1,   ni   = wv >> 1;
  const int bb   = bg * 32 + mi * 16 + (lane & 15);
  const int q8   = (lane >> 4) * 8;
  const int nr   = ni * 16 + (lane & 15);

  // ---------------- prologue ----------------
  {
    const float* src = p.in + (size_t)bA * TS * NN;
    for (int idx = tid; idx < TS * NN; idx += 256) {
      int t = idx >> 7, n = idx & 127;
      ubuf[n * 100 + t] = f2bf(src[idx]);
    }
  }
  __syncthreads();
  {
    int n = tid >> 1, sc = tid & 1;
    int s0 = sc * 50, s1 = sc ? 99 : 50;
    for (int s = s0; s < s1; ++s) {
      float acc = p.b2[s];
      const float* w2r = p.W2 + s * TS;
      const u16* itr = &ubuf[n * 100];
      for (int t = 0; t + 1 < TS; t += 2) {
        acc = fmaf(bf2f(itr[t]),     w2r[t],     acc);
        acc = fmaf(bf2f(itr[t + 1]), w2r[t + 1], acc);
      }
      acc = fmaf(bf2f(itr[98]), w2r[98], acc);
      z2s[n * 100 + s] = f2bf(acc);
    }
  }
  __syncthreads();
  {
    int r = tid >> 3, kc = tid & 7;
    int g = r >> 3, ul = r & 7;
    int grow = g * 256 + js * 8 + ul;
    const float* wihr = p.Wih + (size_t)grow * 128;
    const float* whhr = p.Whh + (size_t)grow * 256;
    for (int k = kc; k < 384; k += 8)
      ubuf[r * 392 + k] = f2bf((k < 128) ? wihr[k] : whhr[k - 128]);
    if (tid < 32) {
      int g2 = tid >> 3, ul2 = tid & 7;
      int gr = g2 * 256 + js * 8 + ul2;
      biasv[tid] = p.bih[gr] + p.bhh[gr];
    }
    for (int idx = tid; idx < 99 * 16; idx += 256) {
      int s = idx >> 4, j = idx & 15;
      int col = (j < 8) ? (js * 8 + j) : (256 + js * 8 + (j - 8));
      W1c[idx] = f2bf(p.W1[s * 512 + col]);
    }
    for (int s = tid; s < 99; s += 256) {
      w3s[s] = p.W3[s];
      b1s[s] = p.b1[s];
    }
  }
  __syncthreads();

  float creg = 0.f;   // LSTM cell state for (lb=tid>>3, ul=tid&7)
  const u16* wslr = &ubuf[nr * 392];

  for (int t = 0; t < TS; ++t) {
    const int par = t & 1;
    // ---- wait: all B(t-1) of the group done (publishes z1part + hbuf) ----
    if (t > 0) {
      if (tid == 0) {
        uint32 tgt = 32u * (uint32)t;
        while (ld32(&p.flagB[bg]) < tgt) __builtin_amdgcn_s_sleep(1);
      }
      __syncthreads();
    }

    // ---- issue h-fragment loads now; consumed after the A phase ----
    ull hq0[8], hq1[8];
    {
      const ull* hrow = (const ull*)(p.hbuf + ((size_t)par * BB + bb) * HH);
      #pragma unroll
      for (int ks = 0; ks < 8; ++ks) {
        int ei = ks * 32 + q8;           // element offset (16B-aligned)
        hq0[ks] = ld64(hrow + (ei >> 2));
        hq1[ks] = ld64(hrow + (ei >> 2) + 1);
      }
    }

    // ================= A phase: attention for batch bA =================
    if (tid < 198) {   // z1 partial sums over 32 js, split in two halves
      int s  = (tid < 99) ? tid : tid - 99;
      int j0 = (tid < 99) ? 0 : 16;
      const float* zp = p.z1part + (((size_t)par * 16 + bg) * 32 + lbA) * 32 * 99;
      float part[16];
      #pragma unroll
      for (int j = 0; j < 16; ++j) part[j] = ldf(zp + (j0 + j) * 99 + s);
      float v = 0.f;
      #pragma unroll
      for (int j = 0; j < 16; ++j) v += part[j];
      zsum[tid] = v;
    }
    __syncthreads();
    if (tid < 99) z1s[tid] = b1s[tid] + zsum[tid] + zsum[99 + tid];
    __syncthreads();
    {  // e[n] = sum_s w3[s] * tanh(z1[s] + z2[n][s])
      int n = tid >> 1, hf = tid & 1;
      int s0 = hf * 50, s1 = hf ? 99 : 50;
      const u16* z2r = &z2s[n * 100];
      float acc = 0.f;
      for (int s = s0; s < s1; ++s) {
        float x = ftanh(z1s[s] + bf2f(z2r[s]));
        acc = fmaf(w3s[s], x, acc);
      }
      uni[tid] = acc;
    }
    __syncthreads();
    // softmax + w, all in wave 0 (no extra barriers)
    float* efin = uni + 256;
    if (tid < 64) {
      float v0 = uni[2 * tid]        + uni[2 * tid + 1];
      float v1 = uni[2 * (tid + 64)] + uni[2 * (tid + 64) + 1];
      efin[tid] = v0; efin[tid + 64] = v1;
      float m = fmaxf(v0, v1);
      for (int off = 32; off; off >>= 1) m = fmaxf(m, __shfl_xor(m, off));
      float sm = __expf(v0 - m) + __expf(v1 - m);
      for (int off = 32; off; off >>= 1) sm += __shfl_xor(sm, off);
      float r = frcp(sm);
      float e0 = efin[2 * tid], e1 = efin[2 * tid + 1];
      const float* xr = p.in + ((size_t)bA * TS + t) * NN + 2 * tid;
      float w0 = __expf(e0 - m) * r * xr[0];
      float w1 = __expf(e1 - m) * r * xr[1];
      float* orow = outw + ((size_t)bA * TS + t) * NN + 2 * tid;
      orow[0] = w0; orow[1] = w1;                      // f32 output (cached)
      st32((uint32*)p.wbf + (size_t)bA * 64 + tid,     // bf16 pair, sc1
           (uint32)f2bf(w0) | ((uint32)f2bf(w1) << 16));
    }
    __builtin_amdgcn_s_waitcnt(0);   // drain wave-0 w-stores to L3
    if (tid == 0) st32(&p.flagA[bA], (uint32)(t + 1));

    // ================= B phase: gates+LSTM for (bg, js) =================
    f4 acc = {0.f, 0.f, 0.f, 0.f};
    #pragma unroll
    for (int ks = 0; ks < 8; ++ks) {   // h-part (fragments already in regs)
      union { ull q[2]; s8v v; } a; a.q[0] = hq0[ks]; a.q[1] = hq1[ks];
      const s8v* bp = (const s8v*)(wslr + 128 + ks * 32 + q8);
      acc = __builtin_amdgcn_mfma_f32_16x16x32_bf16(a.v, *bp, acc, 0, 0, 0);
    }
    if (tid < 32) {   // wait: all A(t) of the group published w
      uint32 tgt = (uint32)(t + 1);
      while (ld32(&p.flagA[bg * 32 + tid]) < tgt) __builtin_amdgcn_s_sleep(1);
    }
    __syncthreads();
    {
      const ull* wrow = (const ull*)(p.wbf + (size_t)bb * NN);
      #pragma unroll
      for (int ks = 0; ks < 4; ++ks) {  // w-part
        int ei = ks * 32 + q8;
        union { ull q[2]; s8v v; } a;
        a.q[0] = ld64(wrow + (ei >> 2));
        a.q[1] = ld64(wrow + (ei >> 2) + 1);
        const s8v* bp = (const s8v*)(wslr + ei);
        acc = __builtin_amdgcn_mfma_f32_16x16x32_bf16(a.v, *bp, acc, 0, 0, 0);
      }
      // C/D: col=lane&15 (weight row), row=(lane>>4)*4+i (batch)  [m89/m91]
      int mrow = mi * 16 + (lane >> 4) * 4;
      #pragma unroll
      for (int i = 0; i < 4; ++i) uni[(mrow + i) * 33 + nr] = acc[i];
    }
    __syncthreads();
    {  // LSTM pointwise: thread = (lb, ul)
      int lb = tid >> 3, ul = tid & 7;
      float iv = uni[lb * 33 + ul]      + biasv[ul];
      float fv = uni[lb * 33 + 8 + ul]  + biasv[8 + ul];
      float gv = uni[lb * 33 + 16 + ul] + biasv[16 + ul];
      float ov = uni[lb * 33 + 24 + ul] + biasv[24 + ul];
      float cn = fsig(fv) * creg + fsig(iv) * ftanh(gv);
      float hn = fsig(ov) * ftanh(cn);
      creg = cn;
      int bb2 = bg * 32 + lb, u = js * 8 + ul;
      oute[((size_t)bb2 * TS + t) * HH + u] = hn;   // f32 output (cached)
      hcn[lb * 16 + ul]     = hn;
      hcn[lb * 16 + 8 + ul] = cn;
    }
    __syncthreads();
    if (tid < 64) {  // pack h (bf16 x4) -> hbuf via sc1
      int lb = tid >> 1, half = tid & 1;
      const float* hh = &hcn[lb * 16 + half * 4];
      ull pk = (ull)f2bf(hh[0]) | ((ull)f2bf(hh[1]) << 16)
             | ((ull)f2bf(hh[2]) << 32) | ((ull)f2bf(hh[3]) << 48);
      ull* hp = (ull*)(p.hbuf + (((size_t)((t + 1) & 1)) * BB + bg * 32 + lb) * HH + js * 8);
      st64(hp + half, pk);
    }
    {  // z1 partial for step t+1 from fresh h,c (16 K-columns)
      int lb = tid >> 3, sc = tid & 7;
      int p2 = (t + 1) & 1;
      float* zp = p.z1part + ((((size_t)p2 * 16 + bg) * 32 + lb) * 32 + js) * 99;
      const float* hc = &hcn[lb * 16];
      for (int s = sc; s < 99; s += 8) {
        const u16* wr = &W1c[s * 16];
        float v = 0.f;
        #pragma unroll
        for (int j = 0; j < 16; ++j) v = fmaf(hc[j], bf2f(wr[j]), v);
        stf(zp + s, v);
      }
    }
    __builtin_amdgcn_s_waitcnt(0);   // drain this wave's h/z1part stores
    __syncthreads();                 // all waves drained
    if (tid == 0)
      __hip_atomic_fetch_add(&p.flagB[bg], 1u, __ATOMIC_RELAXED,
                             __HIP_MEMORY_SCOPE_AGENT);
  }
}

extern "C" void kernel_launch(void* const* d_in, const int* in_sizes, int n_in,
                              void* d_out, int out_size, void* d_ws, size_t ws_size,
                              hipStream_t stream)
{
  KParams p;
  p.in  = (const float*)d_in[0];
  p.W1  = (const float*)d_in[1];
  p.b1  = (const float*)d_in[2];
  p.W2  = (const float*)d_in[3];
  p.b2  = (const float*)d_in[4];
  p.W3  = (const float*)d_in[5];
  // d_in[6] = b3: softmax shift-invariant, unused
  p.Wih = (const float*)d_in[7];
  p.Whh = (const float*)d_in[8];
  p.bih = (const float*)d_in[9];
  p.bhh = (const float*)d_in[10];
  p.out = (float*)d_out;

  char* ws = (char*)d_ws;
  const size_t offFlagB  = 2048;
  const size_t offHbuf   = 4096;
  const size_t hbufBytes = 2ull * BB * HH * 2;                 // 524,288
  const size_t offWbf    = offHbuf + hbufBytes;                // 528,384
  const size_t wbfBytes  = (size_t)BB * NN * 2;                // 131,072
  const size_t offZ1     = offWbf + wbfBytes;                  // 659,456
  const size_t z1Bytes   = 2ull * 16 * 32 * 32 * 99 * 4;       // 12,976,128
  const size_t needBytes = offZ1 + z1Bytes;                    // ~13.6 MB
  if (ws_size < needBytes) return;  // fail loudly (poisoned output)

  p.flagA  = (uint32*)ws;
  p.flagB  = (uint32*)(ws + offFlagB);
  p.hbuf   = (u16*)(ws + offHbuf);
  p.wbf    = (u16*)(ws + offWbf);
  p.z1part = (float*)(ws + offZ1);

  // zero everything the kernel may read before first write
  hipMemsetAsync(d_ws, 0, needBytes, stream);

  enc_kernel<<<dim3(512), dim3(256), 0, stream>>>(p);
}

// Round 5
// 3266.650 us; speedup vs baseline: 8.2391x; 1.6109x over previous
//
#include <hip/hip_runtime.h>

// ============================================================================
// Persistent dataflow kernel for attention-LSTM encoder.
// B=512, T-1=99, N=128, H=256. f32 global I/O, bf16 LDS/MFMA internals.
//
// R5: R4 was bound by the z1part exchange (13 MB/step of fine-grained
// scattered sc1 traffic at ~16x fabric-granule inflation -> 360 GB/s
// effective -> 53us/step). Restructure: B-blocks publish h AND c (bf16,
// coalesced); 7 "z1-blocks" per group compute z1 slices for all 32 group
// batches via MFMA (W1 slice in LDS, hc as coalesced 16B fragments from
// hbuf); A-blocks read a contiguous 396B z1 row. ALL cross-block traffic is
// dwordx4-coalesced relaxed agent-scope (sc1) -> full fabric-line efficiency.
// Extra hop: flagB -> (z1 compute) -> flagZ -> A -> flagA -> B -> flagB.
//
// 512 blocks x 256 threads, 2 blocks/CU (LDS ~75KB => all 512 co-resident).
// Each 32-block group is a closed dependency system => deadlock-free.
// c stays fp32 in registers for the recurrence; bf16 copy only feeds z1.
// ============================================================================

typedef unsigned int  uint32;
typedef unsigned long long ull;
typedef unsigned short u16;
typedef float  f4  __attribute__((ext_vector_type(4)));
typedef short  s8v __attribute__((ext_vector_type(8)));   // 8 bf16

#define TS 99
#define BB 512
#define NN 128
#define HH 256

__device__ __forceinline__ float bf2f(u16 u){
  union { uint32 i; float f; } v; v.i = ((uint32)u) << 16; return v.f;
}
__device__ __forceinline__ u16 f2bf(float f){
  union { float f; uint32 i; } v; v.f = f;
  uint32 r = v.i + 0x7FFFu + ((v.i >> 16) & 1u);   // RNE (finite values only)
  return (u16)(r >> 16);
}
__device__ __forceinline__ float frcp(float x){ return __builtin_amdgcn_rcpf(x); }
__device__ __forceinline__ float ftanh(float x){
  float t = __expf(2.f * x);
  return 1.f - 2.f * frcp(t + 1.f);
}
__device__ __forceinline__ float fsig(float x){
  return frcp(1.f + __expf(-x));
}

// L3-coherence-point accesses (sc1; bypass per-XCD L2, no cache maintenance)
__device__ __forceinline__ uint32 ld32(const uint32* p){
  return __hip_atomic_load(p, __ATOMIC_RELAXED, __HIP_MEMORY_SCOPE_AGENT);
}
__device__ __forceinline__ ull ld64(const ull* p){
  return __hip_atomic_load(p, __ATOMIC_RELAXED, __HIP_MEMORY_SCOPE_AGENT);
}
__device__ __forceinline__ void st32(uint32* p, uint32 v){
  __hip_atomic_store(p, v, __ATOMIC_RELAXED, __HIP_MEMORY_SCOPE_AGENT);
}
__device__ __forceinline__ void st64(ull* p, ull v){
  __hip_atomic_store(p, v, __ATOMIC_RELAXED, __HIP_MEMORY_SCOPE_AGENT);
}
__device__ __forceinline__ float ldf(const float* p){
  union { uint32 i; float f; } v; v.i = ld32((const uint32*)p); return v.f;
}
__device__ __forceinline__ void stf(float* p, float x){
  union { float f; uint32 i; } v; v.f = x; st32((uint32*)p, v.i);
}

struct KParams {
  const float *in, *W1, *b1, *W2, *b2, *W3, *Wih, *Whh, *bih, *bhh;
  float *out;        // [weighted B*99*128 | encoded B*99*256] f32
  uint32 *flagA;     // [512]  A(t) done -> w published
  uint32 *flagB;     // [16]   counts B-phase completions per group
  uint32 *flagZ;     // [16]   counts z1-slice completions per group
  u16 *hbuf;         // [2][512][512] bf16: per batch h[256] | c[256]
  u16 *wbf;          // [512][128] bf16 (single-buffer, race-safe via flags)
  float *z1x;        // [2][512][112] f32 z1 rows (99 used, 112 padded)
};

__global__ __launch_bounds__(256, 2) void enc_kernel(KParams p)
{
  __shared__ __align__(16) u16   z2s[128 * 100];   // z2[n][s] bf16 (+b2)
  __shared__ __align__(16) u16   ubuf[12800];      // in_t[128][100] then Wsl[32][392]
  __shared__ __align__(16) u16   W1s[16 * 520];    // z1-blocks: W1 slice, padded
  __shared__ __align__(16) float uni[1056];        // gates[32][33] | ep[256]+efin[128]
  __shared__ __align__(16) float z1s[100];
  __shared__ __align__(16) float hcn[32 * 16];     // per-batch [h0..7, c0..7]
  __shared__ __align__(16) float w3s[100];
  __shared__ __align__(16) float b1s[100];
  __shared__ __align__(16) float biasv[32];

  const int tid = threadIdx.x;
  const int blk = blockIdx.x;
  const int bA  = blk;        // A-role batch
  const int bg  = blk >> 5;   // group of 32 batches / 32 blocks
  const int js  = blk & 31;   // B-role unit slice (units js*8 .. js*8+7)

  float* outw = p.out;
  float* oute = p.out + (size_t)BB * TS * NN;

  // wave-role constants (MFMA lane mapping, R4-verified)
  const int wv   = tid >> 6, lane = tid & 63;
  const int mi   = wv & 1,   ni   = wv >> 1;
  const int bb   = bg * 32 + mi * 16 + (lane & 15);
  const int q8   = (lane >> 4) * 8;
  const int nr   = ni * 16 + (lane & 15);

  // ---------------- prologue ----------------
  {
    const float* src = p.in + (size_t)bA * TS * NN;
    for (int idx = tid; idx < TS * NN; idx += 256) {
      int t = idx >> 7, n = idx & 127;
      ubuf[n * 100 + t] = f2bf(src[idx]);
    }
  }
  __syncthreads();
  {  // z2s[n][s] = b2[s] + sum_t in_t[n][t] * W2[s][t]
    int n = tid >> 1, sc = tid & 1;
    int s0 = sc * 50, s1 = sc ? 99 : 50;
    for (int s = s0; s < s1; ++s) {
      float acc = p.b2[s];
      const float* w2r = p.W2 + s * TS;
      const u16* itr = &ubuf[n * 100];
      for (int t = 0; t + 1 < TS; t += 2) {
        acc = fmaf(bf2f(itr[t]),     w2r[t],     acc);
        acc = fmaf(bf2f(itr[t + 1]), w2r[t + 1], acc);
      }
      acc = fmaf(bf2f(itr[98]), w2r[98], acc);
      z2s[n * 100 + s] = f2bf(acc);
    }
  }
  __syncthreads();
  {  // Wsl[32 rows][392] into ubuf; W1 slice for z1-blocks; small vectors
    int r = tid >> 3;
    int g = r >> 3, ul = r & 7;
    int grow = g * 256 + js * 8 + ul;
    const float* wihr = p.Wih + (size_t)grow * 128;
    const float* whhr = p.Whh + (size_t)grow * 256;
    for (int k = tid & 7; k < 384; k += 8)
      ubuf[r * 392 + k] = f2bf((k < 128) ? wihr[k] : whhr[k - 128]);
    if (tid < 32) {
      int g2 = tid >> 3, ul2 = tid & 7;
      int gr = g2 * 256 + js * 8 + ul2;
      biasv[tid] = p.bih[gr] + p.bhh[gr];
    }
    if (js < 7) {   // W1s[r16][k512], rows >= 99 zeroed (avoid OOB + NaN)
      for (int idx = tid; idx < 16 * 512; idx += 256) {
        int r2 = idx >> 9, k = idx & 511;
        int sg = js * 16 + r2;
        W1s[r2 * 520 + k] = (sg < TS) ? f2bf(p.W1[(size_t)sg * 512 + k]) : (u16)0;
      }
    }
    for (int s = tid; s < 99; s += 256) {
      w3s[s] = p.W3[s];
      b1s[s] = p.b1[s];
    }
  }
  __syncthreads();

  float creg = 0.f;   // LSTM cell state for (lb=tid>>3, ul=tid&7), fp32 forever

  for (int t = 0; t < TS; ++t) {
    const int par = t & 1;

    // ========= z1 sub-phase: blocks js<7 compute z1 slices via MFMA =========
    if (t > 0 && js < 7) {
      if (tid == 0) {
        uint32 tgt = 32u * (uint32)t;
        while (ld32(&p.flagB[bg]) < tgt) __builtin_amdgcn_s_sleep(1);
      }
      __syncthreads();
      if (wv < 2) {   // wave wv handles batches wv*16..+16 of the group
        int bz = bg * 32 + wv * 16 + (lane & 15);
        const ull* hcrow = (const ull*)(p.hbuf + ((size_t)par * BB + bz) * 512);
        ull f0[16], f1[16];
        #pragma unroll
        for (int ks = 0; ks < 16; ++ks) {
          int ei = ks * 32 + q8;
          f0[ks] = ld64(hcrow + (ei >> 2));
          f1[ks] = ld64(hcrow + (ei >> 2) + 1);
        }
        f4 zacc = {0.f, 0.f, 0.f, 0.f};
        #pragma unroll
        for (int ks = 0; ks < 16; ++ks) {
          union { ull q[2]; s8v v; } a; a.q[0] = f0[ks]; a.q[1] = f1[ks];
          const s8v* bp = (const s8v*)&W1s[(lane & 15) * 520 + ks * 32 + q8];
          zacc = __builtin_amdgcn_mfma_f32_16x16x32_bf16(a.v, *bp, zacc, 0, 0, 0);
        }
        // C: col=lane&15 -> s_local, row=(lane>>4)*4+i -> batch_local
        float* zrow = p.z1x + ((size_t)par * BB + bg * 32 + wv * 16) * 112
                    + js * 16 + (lane & 15);
        int m0 = (lane >> 4) * 4;
        #pragma unroll
        for (int i = 0; i < 4; ++i) stf(zrow + (size_t)(m0 + i) * 112, zacc[i]);
      }
      __builtin_amdgcn_s_waitcnt(0);
      __syncthreads();
      if (tid == 0)
        __hip_atomic_fetch_add(&p.flagZ[bg], 1u, __ATOMIC_RELAXED,
                               __HIP_MEMORY_SCOPE_AGENT);
    }

    // ---- wait: z1 for this step ready (transitively implies h,c ready) ----
    if (t > 0) {
      if (tid == 0) {
        uint32 tgt = 7u * (uint32)t;
        while (ld32(&p.flagZ[bg]) < tgt) __builtin_amdgcn_s_sleep(1);
      }
      __syncthreads();
    }

    // ---- prefetch gates h-operand fragments (consumed in B phase) ----
    ull hq0[8], hq1[8];
    {
      const ull* hrow = (const ull*)(p.hbuf + ((size_t)par * BB + bb) * 512);
      #pragma unroll
      for (int ks = 0; ks < 8; ++ks) {
        int ei = ks * 32 + q8;
        hq0[ks] = ld64(hrow + (ei >> 2));
        hq1[ks] = ld64(hrow + (ei >> 2) + 1);
      }
    }

    // ================= A phase: attention for batch bA =================
    if (tid < 99) {
      float v = b1s[tid];
      if (t > 0) v += ldf(p.z1x + ((size_t)par * BB + bA) * 112 + tid);
      z1s[tid] = v;
    }
    __syncthreads();
    {  // e[n] = sum_s w3[s] * tanh(z1[s] + z2[n][s])
      int n = tid >> 1, hf = tid & 1;
      int s0 = hf * 50, s1 = hf ? 99 : 50;
      const u16* z2r = &z2s[n * 100];
      float acc = 0.f;
      for (int s = s0; s < s1; ++s) {
        float x = ftanh(z1s[s] + bf2f(z2r[s]));
        acc = fmaf(w3s[s], x, acc);
      }
      uni[tid] = acc;
    }
    __syncthreads();
    // softmax + w, all in wave 0
    float* efin = uni + 256;
    if (tid < 64) {
      float v0 = uni[2 * tid]        + uni[2 * tid + 1];
      float v1 = uni[2 * (tid + 64)] + uni[2 * (tid + 64) + 1];
      efin[tid] = v0; efin[tid + 64] = v1;
      float m = fmaxf(v0, v1);
      for (int off = 32; off; off >>= 1) m = fmaxf(m, __shfl_xor(m, off));
      float sm = __expf(v0 - m) + __expf(v1 - m);
      for (int off = 32; off; off >>= 1) sm += __shfl_xor(sm, off);
      float r = frcp(sm);
      float e0 = efin[2 * tid], e1 = efin[2 * tid + 1];
      const float* xr = p.in + ((size_t)bA * TS + t) * NN + 2 * tid;
      float w0 = __expf(e0 - m) * r * xr[0];
      float w1 = __expf(e1 - m) * r * xr[1];
      float* orow = outw + ((size_t)bA * TS + t) * NN + 2 * tid;
      orow[0] = w0; orow[1] = w1;                      // f32 output
      st32((uint32*)p.wbf + (size_t)bA * 64 + tid,     // bf16 pair, sc1
           (uint32)f2bf(w0) | ((uint32)f2bf(w1) << 16));
    }
    __builtin_amdgcn_s_waitcnt(0);   // drain wave-0 w-stores to L3
    if (tid == 0) st32(&p.flagA[bA], (uint32)(t + 1));

    // ================= B phase: gates+LSTM for (bg, js) =================
    const u16* wslr = &ubuf[nr * 392];
    f4 acc = {0.f, 0.f, 0.f, 0.f};
    #pragma unroll
    for (int ks = 0; ks < 8; ++ks) {   // h-part (fragments already in regs)
      union { ull q[2]; s8v v; } a; a.q[0] = hq0[ks]; a.q[1] = hq1[ks];
      const s8v* bp = (const s8v*)(wslr + 128 + ks * 32 + q8);
      acc = __builtin_amdgcn_mfma_f32_16x16x32_bf16(a.v, *bp, acc, 0, 0, 0);
    }
    if (tid < 32) {   // wait: all A(t) of the group published w
      uint32 tgt = (uint32)(t + 1);
      while (ld32(&p.flagA[bg * 32 + tid]) < tgt) __builtin_amdgcn_s_sleep(1);
    }
    __syncthreads();
    {
      const ull* wrow = (const ull*)(p.wbf + (size_t)bb * NN);
      #pragma unroll
      for (int ks = 0; ks < 4; ++ks) {  // w-part
        int ei = ks * 32 + q8;
        union { ull q[2]; s8v v; } a;
        a.q[0] = ld64(wrow + (ei >> 2));
        a.q[1] = ld64(wrow + (ei >> 2) + 1);
        const s8v* bp = (const s8v*)(wslr + ei);
        acc = __builtin_amdgcn_mfma_f32_16x16x32_bf16(a.v, *bp, acc, 0, 0, 0);
      }
      int mrow = mi * 16 + (lane >> 4) * 4;
      #pragma unroll
      for (int i = 0; i < 4; ++i) uni[(mrow + i) * 33 + nr] = acc[i];
    }
    __syncthreads();
    {  // LSTM pointwise: thread = (lb, ul)
      int lb = tid >> 3, ul = tid & 7;
      float iv = uni[lb * 33 + ul]      + biasv[ul];
      float fv = uni[lb * 33 + 8 + ul]  + biasv[8 + ul];
      float gv = uni[lb * 33 + 16 + ul] + biasv[16 + ul];
      float ov = uni[lb * 33 + 24 + ul] + biasv[24 + ul];
      float cn = fsig(fv) * creg + fsig(iv) * ftanh(gv);
      float hn = fsig(ov) * ftanh(cn);
      creg = cn;
      int bb2 = bg * 32 + lb, u = js * 8 + ul;
      oute[((size_t)bb2 * TS + t) * HH + u] = hn;   // f32 output
      hcn[lb * 16 + ul]     = hn;
      hcn[lb * 16 + 8 + ul] = cn;
    }
    __syncthreads();
    if (tid < 128) {  // pack h (tid<64) and c (tid>=64) as bf16x4 -> hbuf
      int q  = tid & 63;
      int lb = q >> 1, half = q & 1;
      int coff = (tid < 64) ? 0 : 8;                 // hcn: h at +0, c at +8
      const float* hh = &hcn[lb * 16 + coff + half * 4];
      ull pk = (ull)f2bf(hh[0]) | ((ull)f2bf(hh[1]) << 16)
             | ((ull)f2bf(hh[2]) << 32) | ((ull)f2bf(hh[3]) << 48);
      int uoff = ((tid < 64) ? 0 : 256) + js * 8;
      ull* hp = (ull*)(p.hbuf
                + (((size_t)((t + 1) & 1)) * BB + bg * 32 + lb) * 512 + uoff);
      st64(hp + half, pk);
    }
    __builtin_amdgcn_s_waitcnt(0);   // drain this wave's h/c stores
    __syncthreads();                 // all waves drained
    if (tid == 0)
      __hip_atomic_fetch_add(&p.flagB[bg], 1u, __ATOMIC_RELAXED,
                             __HIP_MEMORY_SCOPE_AGENT);
  }
}

extern "C" void kernel_launch(void* const* d_in, const int* in_sizes, int n_in,
                              void* d_out, int out_size, void* d_ws, size_t ws_size,
                              hipStream_t stream)
{
  KParams p;
  p.in  = (const float*)d_in[0];
  p.W1  = (const float*)d_in[1];
  p.b1  = (const float*)d_in[2];
  p.W2  = (const float*)d_in[3];
  p.b2  = (const float*)d_in[4];
  p.W3  = (const float*)d_in[5];
  // d_in[6] = b3: softmax shift-invariant, unused
  p.Wih = (const float*)d_in[7];
  p.Whh = (const float*)d_in[8];
  p.bih = (const float*)d_in[9];
  p.bhh = (const float*)d_in[10];
  p.out = (float*)d_out;

  char* ws = (char*)d_ws;
  const size_t offFlagB  = 2048;
  const size_t offFlagZ  = 3072;
  const size_t offHbuf   = 4096;
  const size_t hbufBytes = 2ull * BB * 512 * 2;                // 1,048,576
  const size_t offWbf    = offHbuf + hbufBytes;                // 1,052,672
  const size_t wbfBytes  = (size_t)BB * NN * 2;                // 131,072
  const size_t offZ1x    = offWbf + wbfBytes;                  // 1,183,744
  const size_t z1xBytes  = 2ull * BB * 112 * 4;                // 458,752
  const size_t needBytes = offZ1x + z1xBytes;                  // ~1.64 MB
  if (ws_size < needBytes) return;  // fail loudly (poisoned output)

  p.flagA = (uint32*)ws;
  p.flagB = (uint32*)(ws + offFlagB);
  p.flagZ = (uint32*)(ws + offFlagZ);
  p.hbuf  = (u16*)(ws + offHbuf);
  p.wbf   = (u16*)(ws + offWbf);
  p.z1x   = (float*)(ws + offZ1x);

  // zero everything the kernel may read before first write
  hipMemsetAsync(d_ws, 0, needBytes, stream);

  enc_kernel<<<dim3(512), dim3(256), 0, stream>>>(p);
}